// Round 18
// baseline (122.691 us; speedup 1.0000x reference)
//
#include <hip/hip_runtime.h>

// MHA block: qkv proj -> flash attention -> out proj.  B=4,N=2048,DIM=512,H=8,Dh=64.
// mfma_f32_16x16x32_bf16 fragment mapping (verified m92/m97):
//   A-frag (1st arg): lane holds A[m=base+(lane&15)][k=(lane>>4)*8+b]  -> output ROW
//   B-frag (2nd arg): lane holds B[n=base+(lane&15)][k=(lane>>4)*8+b]  -> output COL
//   C/D  : lane holds C[m=base+(lane>>4)*4+r][n=base+(lane&15)]
// Attention: swapped operands (S^T = mfma(K,Q), O^T = mfma(V^T,P)), log2-domain
// softmax with no max tracking (Q pre-scaled by 0.125*log2e), PV deferred one
// tile, raw v_exp_f32, permlane P-transpose (r17), deferred lsum reduce,
// 32 q per wave (2 subtiles).
// r18: in-block split-KV.  512 threads = 2 groups x 4 waves; group g owns kv
// tiles [g*16, g*16+16) with its own 32KB K/V dbuf (64KB LDS, 2 blocks/CU ->
// 4 waves/SIMD).  No-max softmax makes partial O/lsum additive: group 1
// deposits unnormalized partials in (dead) LDS post-loop, group 0 merges and
// stores.  No extra HBM traffic, no merge kernel.

typedef __bf16 bf16x8 __attribute__((ext_vector_type(8)));
typedef __bf16 bf16x4v __attribute__((ext_vector_type(4)));
typedef float f32x4 __attribute__((ext_vector_type(4)));
typedef unsigned int u32;
typedef unsigned short u16;
typedef u32 u32x2v __attribute__((ext_vector_type(2)));
typedef u32 u32x4v __attribute__((ext_vector_type(4)));

__device__ __forceinline__ u16 f2bf(float f) {
  union { float f; u32 u; } v; v.f = f;
  u32 r = v.u + 0x7FFFu + ((v.u >> 16) & 1u);   // RNE
  return (u16)(r >> 16);
}

// 4x f32 -> packed bf16x4 (v_cvt_pk_bf16_f32 pairs)
__device__ __forceinline__ u32x2v pack4bf(float a, float b, float c, float d) {
  bf16x4v v; v[0] = (__bf16)a; v[1] = (__bf16)b; v[2] = (__bf16)c; v[3] = (__bf16)d;
  return __builtin_bit_cast(u32x2v, v);
}

__device__ __forceinline__ f32x4 mfma16(bf16x8 a, bf16x8 b, f32x4 c) {
  return __builtin_amdgcn_mfma_f32_16x16x32_bf16(a, b, c, 0, 0, 0);
}

// permlane swaps: a' = {a_low, b_low}, b' = {a_high, b_high} (32- or 16-lane rows)
__device__ __forceinline__ void swap32(u32& a, u32& b) {
  u32x2v r = __builtin_amdgcn_permlane32_swap(a, b, false, false);
  a = r[0]; b = r[1];
}
__device__ __forceinline__ void swap16(u32& a, u32& b) {
  u32x2v r = __builtin_amdgcn_permlane16_swap(a, b, false, false);
  a = r[0]; b = r[1];
}

// ---------------- convert f32 -> bf16 ----------------
__global__ void convert_all(const float4* __restrict__ x, const float4* __restrict__ wq,
                            const float4* __restrict__ wo, u16* __restrict__ xb,
                            u16* __restrict__ wqb, u16* __restrict__ wob) {
  int t = blockIdx.x * blockDim.x + threadIdx.x;
  float4 v; u16* dst;
  if (t < 1048576)        { v = x[t];             dst = xb  + (size_t)t * 4; }
  else if (t < 1245184)   { int u = t - 1048576; v = wq[u]; dst = wqb + (size_t)u * 4; }
  else                    { int u = t - 1245184; v = wo[u]; dst = wob + (size_t)u * 4; }
  u32x2v o2;
  o2[0] = (u32)f2bf(v.x) | ((u32)f2bf(v.y) << 16);
  o2[1] = (u32)f2bf(v.z) | ((u32)f2bf(v.w) << 16);
  *(u32x2v*)dst = o2;
}

// ---------------- NT GEMM: C[m,n] = sum_k A[m,k]*B[n,k] ----------------
// MODE 0 (QKV proj): cols <512 (Q) -> bf16 scaled by 0.125*log2e;
//                    cols 512..1023 (K) -> bf16 plain;
//                    cols >=1024 (V) -> TRANSPOSED bf16 to Vt[col-1024][row].
// MODE 1 (out proj): f32 Cf + bias.
template<int MODE>
__global__ __launch_bounds__(256, 2) void gemm_nt(
    const u16* __restrict__ A, const u16* __restrict__ B,
    float* __restrict__ Cf, u16* __restrict__ Cb, u16* __restrict__ Vt,
    const float* __restrict__ bias, int M, int N, int K)
{
  __shared__ __align__(16) u16 As[128 * 64];
  __shared__ __align__(16) u16 Bs[128 * 64];
  const int tid = threadIdx.x;
  const int w = tid >> 6, lane = tid & 63, g = lane >> 4, c = lane & 15;
  const int wr = w >> 1, wc = w & 1;
  const int byy = blockIdx.y;
  const int by = (byy & 7) * 8 + (byy >> 3);     // XCD swizzle (64%8==0)
  const long m0 = (long)by * 128;
  const long n0 = (long)blockIdx.x * 128;
  const f32x4 zero4 = {0.f, 0.f, 0.f, 0.f};

  f32x4 acc[4][4];
#pragma unroll
  for (int i = 0; i < 4; ++i)
#pragma unroll
    for (int j = 0; j < 4; ++j) acc[i][j] = zero4;

  const int srow = tid >> 3;            // 0..31
  const int sch  = (tid & 7) * 8;       // elem offset in row

#pragma unroll 1
  for (int kk = 0; kk < K; kk += 64) {
#pragma unroll
    for (int i = 0; i < 4; ++i) {
      __builtin_amdgcn_global_load_lds(
          (__attribute__((address_space(1))) void*)(A + (m0 + i * 32 + srow) * K + kk + sch),
          (__attribute__((address_space(3))) void*)(As + (i * 32 + w * 8) * 64),
          16, 0, 0);
      __builtin_amdgcn_global_load_lds(
          (__attribute__((address_space(1))) void*)(B + (n0 + i * 32 + srow) * K + kk + sch),
          (__attribute__((address_space(3))) void*)(Bs + (i * 32 + w * 8) * 64),
          16, 0, 0);
    }
    __syncthreads();

#pragma unroll
    for (int ks = 0; ks < 2; ++ks) {
      bf16x8 af[4], bfr[4];
#pragma unroll
      for (int mi = 0; mi < 4; ++mi)
        af[mi] = *(const bf16x8*)&As[(wr * 64 + mi * 16 + c) * 64 + ks * 32 + g * 8];
#pragma unroll
      for (int nj = 0; nj < 4; ++nj)
        bfr[nj] = *(const bf16x8*)&Bs[(wc * 64 + nj * 16 + c) * 64 + ks * 32 + g * 8];
#pragma unroll
      for (int mi = 0; mi < 4; ++mi)
#pragma unroll
        for (int nj = 0; nj < 4; ++nj)
          acc[mi][nj] = mfma16(af[mi], bfr[nj], acc[mi][nj]);
    }
    __syncthreads();
  }

  // epilogue: D row=(lane>>4)*4+r, col=lane&15
#pragma unroll
  for (int mi = 0; mi < 4; ++mi)
#pragma unroll
    for (int nj = 0; nj < 4; ++nj) {
      const long rowb = m0 + wr * 64 + mi * 16 + g * 4;
      const long col  = n0 + wc * 64 + nj * 16 + c;
      if (MODE == 1) {
#pragma unroll
        for (int r = 0; r < 4; ++r)
          Cf[(rowb + r) * N + col] = acc[mi][nj][r] + bias[col];
      } else if (n0 < 512) {
        // Q: fold softmax scale 0.125*log2(e) into the bf16 value
#pragma unroll
        for (int r = 0; r < 4; ++r)
          Cb[(rowb + r) * N + col] = f2bf(acc[mi][nj][r] * 0.18033688f);
      } else if (n0 < 1024) {
#pragma unroll
        for (int r = 0; r < 4; ++r)
          Cb[(rowb + r) * N + col] = f2bf(acc[mi][nj][r]);
      } else {
        // transposed V store: Vt[col-1024][token], r=0..3 consecutive tokens
        u32x2v pk;
        pk[0] = (u32)f2bf(acc[mi][nj][0]) | ((u32)f2bf(acc[mi][nj][1]) << 16);
        pk[1] = (u32)f2bf(acc[mi][nj][2]) | ((u32)f2bf(acc[mi][nj][3]) << 16);
        *(u32x2v*)&Vt[(col - 1024) * 8192 + rowb] = pk;
      }
    }
}

// ---------------- flash attention ----------------
// grid = 512 blocks (32 bh x 16 qb), 512 threads = 2 kv-groups x 4 waves;
// wave owns 32 q (2 subtiles); group g owns kv tiles [g*16, g*16+16).
// LDS: group g at g*32768: K buf = buf*8192, V buf = 16384+buf*8192.
// Post-loop: group 1 deposits unnormalized o/lsum partials; group 0 merges.
__global__ __launch_bounds__(512, 4) void attn_fwd(const u16* __restrict__ qkv,
                                                   const u16* __restrict__ Vt,
                                                   u16* __restrict__ ao)
{
  __shared__ __align__(16) u16 SH[65536 / 2];
  char* const shb = (char*)SH;

  const int tid = threadIdx.x;
  const int w = tid >> 6, lane = tid & 63, g = lane >> 4, c = lane & 15;
  const int g2 = w >> 2;          // kv group 0/1
  const int wq = w & 3;           // q-subtile wave index within group
  const int GB = g2 << 15;        // group LDS byte base (32768)

  // bh-major XCD swizzle (512 % 8 == 0, bijective)
  const int swz = (blockIdx.x & 7) * 64 + (blockIdx.x >> 3);
  const int bh = swz >> 4;
  const int qb = swz & 15;
  const long rowbase = (long)(bh >> 3) * 2048;   // token base for this batch
  const int hcol = (bh & 7) * 64;                // feature base for this head
  const int q0 = qb * 128 + wq * 32;
  const long kvb = (long)g2 * 1024;              // group's first token offset
  const f32x4 zero4 = {0.f, 0.f, 0.f, 0.f};

  // Q B-frags (pre-scaled): Q[q=q0+sub*16+c][d=ks*32+g*8+b]
  bf16x8 qf[2][2];
#pragma unroll
  for (int sub = 0; sub < 2; ++sub)
#pragma unroll
    for (int ks = 0; ks < 2; ++ks)
      qf[sub][ks] = *(const bf16x8*)(qkv + (rowbase + q0 + sub * 16 + c) * 1536 + hcol + ks * 32 + g * 8);

  float lsum[2] = {0.f, 0.f};   // per-lane partials (cross-lane reduce deferred)
  f32x4 o[2][4];
#pragma unroll
  for (int sub = 0; sub < 2; ++sub)
#pragma unroll
    for (int n = 0; n < 4; ++n) o[sub][n] = zero4;

  const u16* kbase = qkv + rowbase * 1536 + 512 + hcol;
  const u16* vtb   = Vt + (long)hcol * 8192 + rowbase;  // V^T[d][token] base

  // staging geometry: wave wq instr j covers tile-rows wq*16+j*8+(lane>>3),
  // source chunk pre-swizzled: (lane&7)^(lane>>3); dest linear lane*16B.
  const int srow8 = lane >> 3;                    // 0..7
  const int schk8 = ((lane & 7) ^ srow8) * 8;     // elem offset of 16B chunk
  const int swzc = (c & 7) << 4;                  // read-side XOR (row&7 == c&7)

  // ---- loop-invariant LDS byte addresses (VGPR), group-based ----
  const int rdG0 = GB + c * 128 + ((g * 16) ^ swzc);        // ks=0 reads
  const int rdG1 = GB + c * 128 + ((64 + g * 16) ^ swzc);   // ks=1 reads

  // ---- running global staging pointers (tile 1 onward) ----
  const long r0 = wq * 16 + srow8;                // j=0 row
  const long r1 = wq * 16 + 8 + srow8;            // j=1 row
  const u16* kp0 = kbase + (kvb + 64 + r0) * 1536 + schk8;
  const u16* kp1 = kbase + (kvb + 64 + r1) * 1536 + schk8;
  const u16* vg0 = vtb + r0 * 8192 + kvb + 64 + schk8;
  const u16* vg1 = vtb + r1 * 8192 + kvb + 64 + schk8;

  // prologue: stage group's tile 0 into buf 0 (K row = token, V row = feature)
  __builtin_amdgcn_global_load_lds(
      (__attribute__((address_space(1))) void*)(kbase + (kvb + r0) * 1536 + schk8),
      (__attribute__((address_space(3))) void*)(shb + GB + (wq * 2 + 0) * 1024), 16, 0, 0);
  __builtin_amdgcn_global_load_lds(
      (__attribute__((address_space(1))) void*)(kbase + (kvb + r1) * 1536 + schk8),
      (__attribute__((address_space(3))) void*)(shb + GB + (wq * 2 + 1) * 1024), 16, 0, 0);
  __builtin_amdgcn_global_load_lds(
      (__attribute__((address_space(1))) void*)(vtb + r0 * 8192 + kvb + schk8),
      (__attribute__((address_space(3))) void*)(shb + GB + 16384 + (wq * 2 + 0) * 1024), 16, 0, 0);
  __builtin_amdgcn_global_load_lds(
      (__attribute__((address_space(1))) void*)(vtb + r1 * 8192 + kvb + schk8),
      (__attribute__((address_space(3))) void*)(shb + GB + 16384 + (wq * 2 + 1) * 1024), 16, 0, 0);
  __syncthreads();

  bf16x8 vp[4][2];   // V^T(t) A-frags (shared by both subtiles), used tile t+1
  bf16x8 pa[2][2];   // P(t) B-frags per subtile, used tile t+1

#pragma unroll 2
  for (int t = 0; t < 16; ++t) {
    const int buf = t & 1;                 // compile-time under unroll-2
    const int KB = buf * 8192;             // K byte base within group (imm)
    const int VB = 16384 + buf * 8192;     // V byte base within group (imm)
    const int KN = 8192 - KB;              // next-buf K base
    const int VN = 16384 + (8192 - (VB - 16384));  // next-buf V base

    // stage tile t+1 into buf^1
    if (t < 15) {
      __builtin_amdgcn_global_load_lds(
          (__attribute__((address_space(1))) void*)kp0,
          (__attribute__((address_space(3))) void*)(shb + GB + KN + (wq * 2 + 0) * 1024), 16, 0, 0);
      __builtin_amdgcn_global_load_lds(
          (__attribute__((address_space(1))) void*)kp1,
          (__attribute__((address_space(3))) void*)(shb + GB + KN + (wq * 2 + 1) * 1024), 16, 0, 0);
      __builtin_amdgcn_global_load_lds(
          (__attribute__((address_space(1))) void*)vg0,
          (__attribute__((address_space(3))) void*)(shb + GB + VN + (wq * 2 + 0) * 1024), 16, 0, 0);
      __builtin_amdgcn_global_load_lds(
          (__attribute__((address_space(1))) void*)vg1,
          (__attribute__((address_space(3))) void*)(shb + GB + VN + (wq * 2 + 1) * 1024), 16, 0, 0);
      kp0 += 64 * 1536; kp1 += 64 * 1536;
      vg0 += 64;        vg1 += 64;
    }

    // PV(t-1): operands fully in regs -> MFMA pipe busy while bk reads fly
    if (t > 0) {
      __builtin_amdgcn_s_setprio(1);
#pragma unroll
      for (int sub = 0; sub < 2; ++sub)
#pragma unroll
        for (int ks = 0; ks < 2; ++ks)
#pragma unroll
          for (int n = 0; n < 4; ++n)
            o[sub][n] = mfma16(vp[n][ks], pa[sub][ks], o[sub][n]);
      __builtin_amdgcn_s_setprio(0);
    }

    // K A-frags: base-reg rdG0/rdG1 + immediate (KB + n*2048)
    bf16x8 bk[4][2];
#pragma unroll
    for (int n = 0; n < 4; ++n) {
      bk[n][0] = *(const bf16x8*)(shb + KB + n * 2048 + rdG0);
      bk[n][1] = *(const bf16x8*)(shb + KB + n * 2048 + rdG1);
    }

    // S^T = K Q^T (log2 units): lane (g,c) gets S[q=sub*16+c][kv=n*16+g*4+r]
    f32x4 s[2][4];
    __builtin_amdgcn_s_setprio(1);
#pragma unroll
    for (int sub = 0; sub < 2; ++sub)
#pragma unroll
      for (int n = 0; n < 4; ++n) {
        f32x4 a0 = zero4;
        a0 = mfma16(bk[n][0], qf[sub][0], a0);
        a0 = mfma16(bk[n][1], qf[sub][1], a0);
        s[sub][n] = a0;
      }
    __builtin_amdgcn_s_setprio(0);

    // softmax: p = 2^s (raw v_exp_f32); per-lane partial sums; then
    // in-register transpose (g' x n) -> (g x slot) via permlane swaps.
#pragma unroll
    for (int sub = 0; sub < 2; ++sub) {
      float rs = 0.f;
      u32 L[4], H[4];
#pragma unroll
      for (int n = 0; n < 4; ++n) {
        float p0 = __builtin_amdgcn_exp2f(s[sub][n][0]);
        float p1 = __builtin_amdgcn_exp2f(s[sub][n][1]);
        float p2 = __builtin_amdgcn_exp2f(s[sub][n][2]);
        float p3 = __builtin_amdgcn_exp2f(s[sub][n][3]);
        rs += (p0 + p1) + (p2 + p3);
        u32x2v pk = pack4bf(p0, p1, p2, p3);
        L[n] = pk[0]; H[n] = pk[1];
      }
      lsum[sub] += rs;
      swap32(L[0], L[1]); swap16(L[0], L[1]);   // -> m0L, m1L (ks=0)
      swap32(H[0], H[1]); swap16(H[0], H[1]);   // -> m0H, m1H (ks=0)
      swap32(L[2], L[3]); swap16(L[2], L[3]);   // -> m0L, m1L (ks=1)
      swap32(H[2], H[3]); swap16(H[2], H[3]);   // -> m0H, m1H (ks=1)
      u32x4v f0 = {L[0], H[0], L[1], H[1]};
      u32x4v f1 = {L[2], H[2], L[3], H[3]};
      pa[sub][0] = __builtin_bit_cast(bf16x8, f0);
      pa[sub][1] = __builtin_bit_cast(bf16x8, f1);
    }

    // read V^T(t) A-frags for next tile's PV (shared by both subtiles)
#pragma unroll
    for (int n = 0; n < 4; ++n) {
      vp[n][0] = *(const bf16x8*)(shb + VB + n * 2048 + rdG0);
      vp[n][1] = *(const bf16x8*)(shb + VB + n * 2048 + rdG1);
    }

    __syncthreads();   // drains vmcnt (stage) + lgkm; buf^1 ready, buf free
  }

  // final PV(15)
  __builtin_amdgcn_s_setprio(1);
#pragma unroll
  for (int sub = 0; sub < 2; ++sub)
#pragma unroll
    for (int ks = 0; ks < 2; ++ks)
#pragma unroll
      for (int n = 0; n < 4; ++n)
        o[sub][n] = mfma16(vp[n][ks], pa[sub][ks], o[sub][n]);
  __builtin_amdgcn_s_setprio(0);

  // ---- cross-group merge (LDS regions dead after final barrier+reg-only PV) ----
  // o region: wave m at m*8192 + lane*128 (XOR'd 16B slots); lsum at 32768+.
  const int mxor = (lane & 7) << 4;
  if (g2 == 1) {
    char* mb = shb + (wq << 13) + lane * 128;
#pragma unroll
    for (int sub = 0; sub < 2; ++sub)
#pragma unroll
      for (int n = 0; n < 4; ++n)
        *(f32x4*)(mb + (((sub * 4 + n) * 16) ^ mxor)) = o[sub][n];
    *(float2*)(shb + 32768 + (wq << 9) + lane * 8) = make_float2(lsum[0], lsum[1]);
  }
  __syncthreads();
  if (g2 == 0) {
    const char* mb = shb + (wq << 13) + lane * 128;
#pragma unroll
    for (int sub = 0; sub < 2; ++sub)
#pragma unroll
      for (int n = 0; n < 4; ++n)
        o[sub][n] += *(const f32x4*)(mb + (((sub * 4 + n) * 16) ^ mxor));
    float2 lo = *(const float2*)(shb + 32768 + (wq << 9) + lane * 8);
    lsum[0] += lo.x; lsum[1] += lo.y;

    // deferred lsum reduction + epilogue per subtile
#pragma unroll
    for (int sub = 0; sub < 2; ++sub) {
      float ls = lsum[sub];
      ls += __shfl_xor(ls, 16);
      ls += __shfl_xor(ls, 32);
      const float linv = 1.0f / ls;
      u16* aor = ao + (rowbase + q0 + sub * 16 + c) * 512 + hcol;
#pragma unroll
      for (int n = 0; n < 4; ++n) {
        u32x2v pk = pack4bf(o[sub][n][0] * linv, o[sub][n][1] * linv,
                            o[sub][n][2] * linv, o[sub][n][3] * linv);
        *(u32x2v*)&aor[n * 16 + g * 4] = pk;
      }
    }
  }
}

extern "C" void kernel_launch(void* const* d_in, const int* in_sizes, int n_in,
                              void* d_out, int out_size, void* d_ws, size_t ws_size,
                              hipStream_t stream) {
  (void)in_sizes; (void)n_in; (void)out_size; (void)ws_size;
  const float* x    = (const float*)d_in[0];
  const float* wqkv = (const float*)d_in[1];
  const float* wout = (const float*)d_in[2];
  const float* bout = (const float*)d_in[3];

  char* ws = (char*)d_ws;
  // layout (MiB): Xb@0 (8), Wqb@8 (1.5), Wob@9.5 (0.5), QKV@10 (24), Vt@34 (8).
  // AO aliases Xb (dead after gemm0; rewritten by convert each call).
  u16* Xb  = (u16*)(ws);
  u16* Wqb = (u16*)(ws + (8ull << 20));
  u16* Wob = (u16*)(ws + (9ull << 20) + (512ull << 10));
  u16* QKV = (u16*)(ws + (10ull << 20));
  u16* Vt  = (u16*)(ws + (34ull << 20));
  u16* AO  = (u16*)(ws);

  convert_all<<<5120, 256, 0, stream>>>((const float4*)x, (const float4*)wqkv,
                                        (const float4*)wout, Xb, Wqb, Wob);
  gemm_nt<0><<<dim3(12, 64), 256, 0, stream>>>(Xb, Wqb, nullptr, QKV, Vt, nullptr, 8192, 1536, 512);
  attn_fwd<<<512, 512, 0, stream>>>(QKV, Vt, AO);
  gemm_nt<1><<<dim3(4, 64), 256, 0, stream>>>(AO, Wob, (float*)d_out, nullptr, nullptr, bout, 8192, 512, 512);
}